// Round 2
// baseline (644.928 us; speedup 1.0000x reference)
//
#include <hip/hip_runtime.h>
#include <hip/hip_bf16.h>
#include <cstdint>

#define B_DIM 4096
#define H_DIM 2048
#define I_DIM 2048
#define K_DIM 4096   // combined = H + I
#define N4    8192   // 4 * H

typedef unsigned int u32;
typedef unsigned short u16;
typedef __attribute__((ext_vector_type(4))) float floatx4;
typedef __attribute__((ext_vector_type(8))) short bf16x8;
typedef __attribute__((ext_vector_type(8))) unsigned short ushort8_t;

__device__ static inline u16 f2bf(float f) {
    union { float f; u32 u; } v; v.f = f;
    u32 u = v.u;
    return (u16)((u + 0x7FFFu + ((u >> 16) & 1u)) >> 16);  // RNE
}
__device__ static inline void gload16(const void* g, void* l) {
    __builtin_amdgcn_global_load_lds(
        (const __attribute__((address_space(1))) u32*)g,
        (__attribute__((address_space(3))) u32*)l, 16, 0, 0);
}
__device__ static inline float fast_sig(float x) {
    return 1.f / (1.f + __expf(-x));
}
__device__ static inline float fast_tanh(float x) {
    float ax = fabsf(x);
    float t = __expf(-2.f * ax);
    float r = (1.f - t) / (1.f + t);
    return copysignf(r, x);
}

// ---------------------------------------------------------------------------
// Kernel 1: both conversions in one dispatch.
//  blocks [0, 8192):      comb[4096][4096] = bf16(concat([h_prev, x_t], dim=1))
//  blocks [8192, 24576):  wb[8192][4096]   = bf16(concat([W_f,W_i,W_c,W_o], dim=0))
//  8 elems / thread, 16B stores.
// ---------------------------------------------------------------------------
__global__ void convert_all(const float* __restrict__ h_prev, const float* __restrict__ x_t,
                            const float* __restrict__ Wf, const float* __restrict__ Wi,
                            const float* __restrict__ Wc, const float* __restrict__ Wo,
                            u16* __restrict__ comb, u16* __restrict__ wb) {
    const int bid = blockIdx.x;
    const float* src;
    u16* dst;
    size_t base;
    if (bid < 8192) {
        base = ((size_t)bid * 256 + threadIdx.x) * 8;
        int row = (int)(base >> 12), col = (int)(base & 4095);
        src = (col < H_DIM) ? h_prev + (size_t)row * H_DIM + col
                            : x_t    + (size_t)row * I_DIM + (col - H_DIM);
        dst = comb + base;
    } else {
        base = ((size_t)(bid - 8192) * 256 + threadIdx.x) * 8;
        int row = (int)(base >> 12), col = (int)(base & 4095);
        int g = row >> 11, jj = row & 2047;
        const float* W = (g == 0) ? Wf : (g == 1) ? Wi : (g == 2) ? Wc : Wo;
        src = W + (size_t)jj * K_DIM + col;
        dst = wb + base;
    }
    float4 v0 = *(const float4*)src;
    float4 v1 = *(const float4*)(src + 4);
    ushort8_t o = { f2bf(v0.x), f2bf(v0.y), f2bf(v0.z), f2bf(v0.w),
                    f2bf(v1.x), f2bf(v1.y), f2bf(v1.z), f2bf(v1.w) };
    *(ushort8_t*)dst = o;
}

// ---------------------------------------------------------------------------
// Kernel 2: fused GEMM + LSTM epilogue.
// m97 structure: 128x128 tile, BK=32, global_load_lds x16, mfma 16x16x32 bf16.
// Column mapping: block covers 32 j's x 4 gates (128 cols). LDS B row rB holds
// W row  g*2048 + jb + (rB>>6)*16 + (rB&15), g=(rB>>4)&3.  =>  each lane's
// bfr[0..3] are gates f,i,c,o for the SAME j -> LSTM math fully in-register.
// XOR swizzle: LDS slot (row, kc) holds global K-chunk kc^(row&3); fragment
// reads at chunk quad^(r&3). Spreads each quad over 16 banks (was 8).
// ---------------------------------------------------------------------------
__global__ __launch_bounds__(256) void gemm_lstm(const u16* __restrict__ A,
                                                 const u16* __restrict__ Bm,
                                                 const float* __restrict__ c_prev,
                                                 const float* __restrict__ bf_,
                                                 const float* __restrict__ bi_,
                                                 const float* __restrict__ bc_,
                                                 const float* __restrict__ bo_,
                                                 float* __restrict__ out) {
    __shared__ u16 lsA[128 * 32];
    __shared__ u16 lsB[128 * 32];

    const int tid   = threadIdx.x;
    const int lane  = tid & 63;
    const int wave  = tid >> 6;
    const int wm    = (wave & 1) * 64;   // batch-row base within tile
    const int wpart = wave >> 1;         // 0/1: j half
    const int wn    = wpart * 64;        // LDS B row base
    const int quad  = lane >> 4;         // 0..3
    const int r     = lane & 15;         // 0..15
    const int mb    = blockIdx.y * 128;  // batch tile
    const int jb    = blockIdx.x * 32;   // j tile (over 2048)

    floatx4 acc[4][4];
#pragma unroll
    for (int i = 0; i < 4; i++)
#pragma unroll
        for (int g = 0; g < 4; g++)
            acc[i][g] = (floatx4){0.f, 0.f, 0.f, 0.f};

    for (int kt = 0; kt < K_DIM; kt += 32) {
        __syncthreads();
#pragma unroll
        for (int s = 0; s < 2; s++) {
            int c   = tid + s * 256;                  // chunk 0..511, 16B each
            int row = c >> 2;                         // 0..127
            int ko  = ((c & 3) ^ (row & 3)) * 8;      // swizzled K-chunk
            gload16(A + (size_t)(mb + row) * K_DIM + kt + ko, (char*)lsA + c * 16);
            int g    = (row >> 4) & 3;
            int wrow = g * H_DIM + jb + ((row >> 6) << 4) + (row & 15);
            gload16(Bm + (size_t)wrow * K_DIM + kt + ko, (char*)lsB + c * 16);
        }
        __syncthreads();

        const int sw = (quad ^ (r & 3)) * 8;
        bf16x8 af[4], bfr[4];
#pragma unroll
        for (int i = 0; i < 4; i++)
            af[i] = *(const bf16x8*)&lsA[(wm + i * 16 + r) * 32 + sw];
#pragma unroll
        for (int g = 0; g < 4; g++)
            bfr[g] = *(const bf16x8*)&lsB[(wn + g * 16 + r) * 32 + sw];
#pragma unroll
        for (int i = 0; i < 4; i++)
#pragma unroll
            for (int g = 0; g < 4; g++)
                acc[i][g] = __builtin_amdgcn_mfma_f32_16x16x32_bf16(
                    af[i], bfr[g], acc[i][g], 0, 0, 0);
    }

    // In-register LSTM epilogue.
    // C/D layout: col = lane&15 (j), row = quad*4 + reg  [m89/m91-verified]
    const int j = jb + wpart * 16 + r;
    const float bfv = bf_[j], biv = bi_[j], bcv = bc_[j], bov = bo_[j];
#pragma unroll
    for (int i = 0; i < 4; i++) {
        int row0 = mb + wm + i * 16 + quad * 4;
#pragma unroll
        for (int rg = 0; rg < 4; rg++) {
            int row = row0 + rg;
            float gf = acc[i][0][rg] + bfv;
            float gi = acc[i][1][rg] + biv;
            float gc = acc[i][2][rg] + bcv;
            float go = acc[i][3][rg] + bov;
            float f  = fast_sig(gf);
            float ii = fast_sig(gi);
            float ct = fast_tanh(gc);
            float oo = fast_sig(go);
            size_t idx = (size_t)row * H_DIM + j;
            float c = f * c_prev[idx] + ii * ct;
            float h = oo * fast_tanh(c);
            out[idx] = h;
            out[(size_t)B_DIM * H_DIM + idx] = c;
        }
    }
}

// ---------------------------------------------------------------------------
// Fallback (only if ws_size < 96 MiB): naive fp32, correct but slow.
// ---------------------------------------------------------------------------
__global__ void lstm_naive(const float* __restrict__ x_t, const float* __restrict__ h_prev,
                           const float* __restrict__ c_prev,
                           const float* __restrict__ Wf, const float* __restrict__ bf_,
                           const float* __restrict__ Wi, const float* __restrict__ bi_,
                           const float* __restrict__ Wc, const float* __restrict__ bc_,
                           const float* __restrict__ Wo, const float* __restrict__ bo_,
                           float* __restrict__ out) {
    int j = blockIdx.x * blockDim.x + threadIdx.x;  // 0..2047
    int b = blockIdx.y;                             // 0..4095
    const float* hrow = h_prev + (long long)b * H_DIM;
    const float* xrow = x_t   + (long long)b * I_DIM;
    const float* wf = Wf + (long long)j * K_DIM;
    const float* wi = Wi + (long long)j * K_DIM;
    const float* wc = Wc + (long long)j * K_DIM;
    const float* wo = Wo + (long long)j * K_DIM;
    float af = bf_[j], ai = bi_[j], ac = bc_[j], ao = bo_[j];
    for (int k = 0; k < H_DIM; k += 4) {
        float4 v = *(const float4*)(hrow + k);
        float4 a = *(const float4*)(wf + k);
        float4 bqi = *(const float4*)(wi + k);
        float4 cq = *(const float4*)(wc + k);
        float4 dq = *(const float4*)(wo + k);
        af += v.x*a.x + v.y*a.y + v.z*a.z + v.w*a.w;
        ai += v.x*bqi.x + v.y*bqi.y + v.z*bqi.z + v.w*bqi.w;
        ac += v.x*cq.x + v.y*cq.y + v.z*cq.z + v.w*cq.w;
        ao += v.x*dq.x + v.y*dq.y + v.z*dq.z + v.w*dq.w;
    }
    for (int k = 0; k < I_DIM; k += 4) {
        float4 v = *(const float4*)(xrow + k);
        float4 a = *(const float4*)(wf + H_DIM + k);
        float4 bqi = *(const float4*)(wi + H_DIM + k);
        float4 cq = *(const float4*)(wc + H_DIM + k);
        float4 dq = *(const float4*)(wo + H_DIM + k);
        af += v.x*a.x + v.y*a.y + v.z*a.z + v.w*a.w;
        ai += v.x*bqi.x + v.y*bqi.y + v.z*bqi.z + v.w*bqi.w;
        ac += v.x*cq.x + v.y*cq.y + v.z*cq.z + v.w*cq.w;
        ao += v.x*dq.x + v.y*dq.y + v.z*dq.z + v.w*dq.w;
    }
    float f  = 1.f / (1.f + __expf(-af));
    float ii = 1.f / (1.f + __expf(-ai));
    float ct = tanhf(ac);
    float oo = 1.f / (1.f + __expf(-ao));
    int t = b * H_DIM + j;
    float c = f * c_prev[t] + ii * ct;
    out[t] = oo * tanhf(c);
    out[B_DIM * H_DIM + t] = c;
}

extern "C" void kernel_launch(void* const* d_in, const int* in_sizes, int n_in,
                              void* d_out, int out_size, void* d_ws, size_t ws_size,
                              hipStream_t stream) {
    const float* x_t    = (const float*)d_in[0];
    const float* h_prev = (const float*)d_in[1];
    const float* c_prev = (const float*)d_in[2];
    const float* Wf = (const float*)d_in[3];  const float* bf_ = (const float*)d_in[4];
    const float* Wi = (const float*)d_in[5];  const float* bi_ = (const float*)d_in[6];
    const float* Wc = (const float*)d_in[7];  const float* bc_ = (const float*)d_in[8];
    const float* Wo = (const float*)d_in[9];  const float* bo_ = (const float*)d_in[10];
    float* out = (float*)d_out;

    const size_t comb_elems = (size_t)B_DIM * K_DIM;   // 16.7M u16
    const size_t wb_elems   = (size_t)N4 * K_DIM;      // 33.5M u16
    const size_t need = (comb_elems + wb_elems) * sizeof(u16);  // 96 MiB

    if (ws_size >= need) {
        u16* comb = (u16*)d_ws;
        u16* wb   = comb + comb_elems;
        convert_all<<<24576, 256, 0, stream>>>(h_prev, x_t, Wf, Wi, Wc, Wo, comb, wb);
        dim3 grid(H_DIM / 32, B_DIM / 128);  // (64, 32)
        gemm_lstm<<<grid, 256, 0, stream>>>(comb, wb, c_prev, bf_, bi_, bc_, bo_, out);
    } else {
        dim3 grid(H_DIM / 256, B_DIM);
        lstm_naive<<<grid, 256, 0, stream>>>(x_t, h_prev, c_prev,
                                             Wf, bf_, Wi, bi_, Wc, bc_, Wo, bo_, out);
    }
}

// Round 3
// 644.122 us; speedup vs baseline: 1.0013x; 1.0013x over previous
//
#include <hip/hip_runtime.h>
#include <hip/hip_bf16.h>
#include <cstdint>

#define B_DIM 4096
#define H_DIM 2048
#define I_DIM 2048
#define K_DIM 4096   // combined = H + I
#define N4    8192   // 4 * H

typedef unsigned int u32;
typedef unsigned short u16;
typedef __attribute__((ext_vector_type(4))) float floatx4;
typedef __attribute__((ext_vector_type(8))) short bf16x8;

__device__ static inline u16 f2bf(float f) {
    union { float f; u32 u; } v; v.f = f;
    u32 u = v.u;
    return (u16)((u + 0x7FFFu + ((u >> 16) & 1u)) >> 16);  // RNE
}
__device__ static inline void gload16(const void* g, void* l) {
    __builtin_amdgcn_global_load_lds(
        (const __attribute__((address_space(1))) u32*)g,
        (__attribute__((address_space(3))) u32*)l, 16, 0, 0);
}
__device__ static inline float fast_sig(float x) {
    return 1.f / (1.f + __expf(-x));
}
__device__ static inline float fast_tanh(float x) {
    float ax = fabsf(x);
    float t = __expf(-2.f * ax);
    float r = (1.f - t) / (1.f + t);
    return copysignf(r, x);
}

// ---------------------------------------------------------------------------
// Kernel 1: both conversions, one dispatch, 4 elems/thread (16B loads).
//  blocks [0, 16384):       comb[4096][4096] = bf16(concat([h_prev, x_t], 1))
//  blocks [16384, 49152):   wb[8192][4096]   = bf16(W), GATE-PERMUTED rows:
//    wb row n  <-  W_g row j,  where (within n's 128-row group)
//       row128 = n & 127,  g = (row128>>4)&3,
//       j = (n>>7)*32 + ((row128>>6)<<4) + (row128&15)
//  This bakes the 4-gate interleave into storage so the GEMM can read wb rows
//  CONTIGUOUSLY (R1's L2-friendly pattern) while each lane's 4 B-fragments
//  are gates f,i,c,o of the SAME j.
//  All selection branches are block-uniform (block = quarter-row).
// ---------------------------------------------------------------------------
__global__ void convert_all(const float* __restrict__ h_prev, const float* __restrict__ x_t,
                            const float* __restrict__ Wf, const float* __restrict__ Wi,
                            const float* __restrict__ Wc, const float* __restrict__ Wo,
                            u16* __restrict__ comb, u16* __restrict__ wb) {
    const int bid = blockIdx.x;
    const float* src;
    u16* dst;
    if (bid < 16384) {
        int base = (bid * 256 + (int)threadIdx.x) * 4;   // < 2^24
        int row = base >> 12, col = base & 4095;
        src = (col < H_DIM) ? h_prev + (size_t)row * H_DIM + col
                            : x_t    + (size_t)row * I_DIM + (col - H_DIM);
        dst = comb + base;
    } else {
        long long base = ((long long)(bid - 16384) * 256 + threadIdx.x) * 4;
        int n = (int)(base >> 12), col = (int)(base & 4095);
        int row128 = n & 127;
        int g = (row128 >> 4) & 3;
        int j = (n >> 7) * 32 + ((row128 >> 6) << 4) + (row128 & 15);
        const float* W = (g == 0) ? Wf : (g == 1) ? Wi : (g == 2) ? Wc : Wo;
        src = W + (size_t)j * K_DIM + col;
        dst = wb + base;
    }
    float4 v = *(const float4*)src;
    ushort4 o = { f2bf(v.x), f2bf(v.y), f2bf(v.z), f2bf(v.w) };
    *(ushort4*)dst = o;
}

// ---------------------------------------------------------------------------
// Kernel 2: fused GEMM + LSTM epilogue.
// m97 structure: 128x128 tile, BK=32, global_load_lds x16, mfma 16x16x32 bf16.
// B rows loaded CONTIGUOUSLY from gate-permuted wb. Per wave (wpart = j-half):
// fragment fg of lane (quad, r) covers wb row nbT + wpart*64 + fg*16 + r
//   -> gate = fg, j = blockIdx.x*32 + wpart*16 + r
// so bfr[0..3] = f,i,c,o gate columns for one j -> LSTM math in-register.
// ---------------------------------------------------------------------------
__global__ __launch_bounds__(256) void gemm_lstm(const u16* __restrict__ A,
                                                 const u16* __restrict__ Bm,
                                                 const float* __restrict__ c_prev,
                                                 const float* __restrict__ bf_,
                                                 const float* __restrict__ bi_,
                                                 const float* __restrict__ bc_,
                                                 const float* __restrict__ bo_,
                                                 float* __restrict__ out) {
    __shared__ u16 lsA[128 * 32];
    __shared__ u16 lsB[128 * 32];

    const int tid   = threadIdx.x;
    const int lane  = tid & 63;
    const int wave  = tid >> 6;
    const int wm    = (wave & 1) * 64;   // batch-row base within tile
    const int wpart = wave >> 1;         // 0/1: j half
    const int wn    = wpart * 64;        // LDS B row base
    const int quad  = lane >> 4;         // 0..3
    const int r     = lane & 15;         // 0..15
    const int mb    = blockIdx.y * 128;  // batch tile
    const int nbT   = blockIdx.x * 128;  // wb row tile (contiguous)
    const int jb    = blockIdx.x * 32;   // j tile (over 2048)

    floatx4 acc[4][4];
#pragma unroll
    for (int i = 0; i < 4; i++)
#pragma unroll
        for (int g = 0; g < 4; g++)
            acc[i][g] = (floatx4){0.f, 0.f, 0.f, 0.f};

    for (int kt = 0; kt < K_DIM; kt += 32) {
        __syncthreads();
#pragma unroll
        for (int s = 0; s < 2; s++) {
            int c   = tid + s * 256;          // chunk 0..511, 16B each
            int row = c >> 2;                 // 0..127
            int ko  = (c & 3) * 8;            // bf16 elems
            gload16(A  + (size_t)(mb + row) * K_DIM + kt + ko, (char*)lsA + c * 16);
            gload16(Bm + (size_t)(nbT + row) * K_DIM + kt + ko, (char*)lsB + c * 16);
        }
        __syncthreads();

        bf16x8 af[4], bfr[4];
#pragma unroll
        for (int i = 0; i < 4; i++)
            af[i] = *(const bf16x8*)&lsA[(wm + i * 16 + r) * 32 + quad * 8];
#pragma unroll
        for (int g = 0; g < 4; g++)
            bfr[g] = *(const bf16x8*)&lsB[(wn + g * 16 + r) * 32 + quad * 8];
#pragma unroll
        for (int i = 0; i < 4; i++)
#pragma unroll
            for (int g = 0; g < 4; g++)
                acc[i][g] = __builtin_amdgcn_mfma_f32_16x16x32_bf16(
                    af[i], bfr[g], acc[i][g], 0, 0, 0);
    }

    // In-register LSTM epilogue.
    // C/D layout: col = lane&15 (j within fragment), row = quad*4 + reg.
    const int j = jb + wpart * 16 + r;
    const float bfv = bf_[j], biv = bi_[j], bcv = bc_[j], bov = bo_[j];
#pragma unroll
    for (int i = 0; i < 4; i++) {
        int row0 = mb + wm + i * 16 + quad * 4;
#pragma unroll
        for (int rg = 0; rg < 4; rg++) {
            int row = row0 + rg;
            float gf = acc[i][0][rg] + bfv;
            float gi = acc[i][1][rg] + biv;
            float gc = acc[i][2][rg] + bcv;
            float go = acc[i][3][rg] + bov;
            float f  = fast_sig(gf);
            float ii = fast_sig(gi);
            float ct = fast_tanh(gc);
            float oo = fast_sig(go);
            size_t idx = (size_t)row * H_DIM + j;
            float c = f * c_prev[idx] + ii * ct;
            float h = oo * fast_tanh(c);
            out[idx] = h;
            out[(size_t)B_DIM * H_DIM + idx] = c;
        }
    }
}

// ---------------------------------------------------------------------------
// Fallback (only if ws_size < 96 MiB): naive fp32, correct but slow.
// ---------------------------------------------------------------------------
__global__ void lstm_naive(const float* __restrict__ x_t, const float* __restrict__ h_prev,
                           const float* __restrict__ c_prev,
                           const float* __restrict__ Wf, const float* __restrict__ bf_,
                           const float* __restrict__ Wi, const float* __restrict__ bi_,
                           const float* __restrict__ Wc, const float* __restrict__ bc_,
                           const float* __restrict__ Wo, const float* __restrict__ bo_,
                           float* __restrict__ out) {
    int j = blockIdx.x * blockDim.x + threadIdx.x;  // 0..2047
    int b = blockIdx.y;                             // 0..4095
    const float* hrow = h_prev + (long long)b * H_DIM;
    const float* xrow = x_t   + (long long)b * I_DIM;
    const float* wf = Wf + (long long)j * K_DIM;
    const float* wi = Wi + (long long)j * K_DIM;
    const float* wc = Wc + (long long)j * K_DIM;
    const float* wo = Wo + (long long)j * K_DIM;
    float af = bf_[j], ai = bi_[j], ac = bc_[j], ao = bo_[j];
    for (int k = 0; k < H_DIM; k += 4) {
        float4 v = *(const float4*)(hrow + k);
        float4 a = *(const float4*)(wf + k);
        float4 bqi = *(const float4*)(wi + k);
        float4 cq = *(const float4*)(wc + k);
        float4 dq = *(const float4*)(wo + k);
        af += v.x*a.x + v.y*a.y + v.z*a.z + v.w*a.w;
        ai += v.x*bqi.x + v.y*bqi.y + v.z*bqi.z + v.w*bqi.w;
        ac += v.x*cq.x + v.y*cq.y + v.z*cq.z + v.w*cq.w;
        ao += v.x*dq.x + v.y*dq.y + v.z*dq.z + v.w*dq.w;
    }
    for (int k = 0; k < I_DIM; k += 4) {
        float4 v = *(const float4*)(xrow + k);
        float4 a = *(const float4*)(wf + H_DIM + k);
        float4 bqi = *(const float4*)(wi + H_DIM + k);
        float4 cq = *(const float4*)(wc + H_DIM + k);
        float4 dq = *(const float4*)(wo + H_DIM + k);
        af += v.x*a.x + v.y*a.y + v.z*a.z + v.w*a.w;
        ai += v.x*bqi.x + v.y*bqi.y + v.z*bqi.z + v.w*bqi.w;
        ac += v.x*cq.x + v.y*cq.y + v.z*cq.z + v.w*cq.w;
        ao += v.x*dq.x + v.y*dq.y + v.z*dq.z + v.w*dq.w;
    }
    float f  = 1.f / (1.f + __expf(-af));
    float ii = 1.f / (1.f + __expf(-ai));
    float ct = tanhf(ac);
    float oo = 1.f / (1.f + __expf(-ao));
    int t = b * H_DIM + j;
    float c = f * c_prev[t] + ii * ct;
    out[t] = oo * tanhf(c);
    out[B_DIM * H_DIM + t] = c;
}

extern "C" void kernel_launch(void* const* d_in, const int* in_sizes, int n_in,
                              void* d_out, int out_size, void* d_ws, size_t ws_size,
                              hipStream_t stream) {
    const float* x_t    = (const float*)d_in[0];
    const float* h_prev = (const float*)d_in[1];
    const float* c_prev = (const float*)d_in[2];
    const float* Wf = (const float*)d_in[3];  const float* bf_ = (const float*)d_in[4];
    const float* Wi = (const float*)d_in[5];  const float* bi_ = (const float*)d_in[6];
    const float* Wc = (const float*)d_in[7];  const float* bc_ = (const float*)d_in[8];
    const float* Wo = (const float*)d_in[9];  const float* bo_ = (const float*)d_in[10];
    float* out = (float*)d_out;

    const size_t comb_elems = (size_t)B_DIM * K_DIM;   // 16.7M u16
    const size_t wb_elems   = (size_t)N4 * K_DIM;      // 33.5M u16
    const size_t need = (comb_elems + wb_elems) * sizeof(u16);  // 96 MiB

    if (ws_size >= need) {
        u16* comb = (u16*)d_ws;
        u16* wb   = comb + comb_elems;
        convert_all<<<49152, 256, 0, stream>>>(h_prev, x_t, Wf, Wi, Wc, Wo, comb, wb);
        dim3 grid(N4 / 128, B_DIM / 128);  // (64, 32)
        gemm_lstm<<<grid, 256, 0, stream>>>(comb, wb, c_prev, bf_, bi_, bc_, bo_, out);
    } else {
        dim3 grid(H_DIM / 256, B_DIM);
        lstm_naive<<<grid, 256, 0, stream>>>(x_t, h_prev, c_prev,
                                             Wf, bf_, Wi, bi_, Wc, bc_, Wo, bo_, out);
    }
}

// Round 4
// 569.182 us; speedup vs baseline: 1.1331x; 1.1317x over previous
//
#include <hip/hip_runtime.h>
#include <hip/hip_bf16.h>
#include <cstdint>

#define B_DIM 4096
#define H_DIM 2048
#define I_DIM 2048
#define K_DIM 4096   // combined = H + I
#define N4    8192   // 4 * H

typedef unsigned int u32;
typedef unsigned short u16;
typedef __attribute__((ext_vector_type(4))) float floatx4;
typedef __attribute__((ext_vector_type(8))) short bf16x8;
typedef __attribute__((ext_vector_type(8))) unsigned short ushort8_t;

__device__ static inline u16 f2bf(float f) {
    union { float f; u32 u; } v; v.f = f;
    u32 u = v.u;
    return (u16)((u + 0x7FFFu + ((u >> 16) & 1u)) >> 16);  // RNE
}
__device__ static inline void gload16(const void* g, void* l) {
    __builtin_amdgcn_global_load_lds(
        (const __attribute__((address_space(1))) u32*)g,
        (__attribute__((address_space(3))) u32*)l, 16, 0, 0);
}
__device__ static inline float fast_sig(float x) {
    return 1.f / (1.f + __expf(-x));
}
__device__ static inline float fast_tanh(float x) {
    float ax = fabsf(x);
    float t = __expf(-2.f * ax);
    float r = (1.f - t) / (1.f + t);
    return copysignf(r, x);
}

// ---------------------------------------------------------------------------
// Kernel 1: both conversions, one dispatch, 8 elems/thread (2x16B loads,
// 16B store).  [R2's non-GEMM time was ~30us lower with 8-elem than 4-elem]
//  blocks [0, 8192):       comb[4096][4096] = bf16(concat([h_prev, x_t], 1))
//  blocks [8192, 24576):   wb[8192][4096]   = bf16(W), GATE-PERMUTED rows:
//    wb row n  <-  W_g row j:  row128 = n & 127, g = (row128>>4)&3,
//                              j = (n>>7)*32 + ((row128>>6)<<4) + (row128&15)
//  The permutation bakes the 4-gate interleave into storage so the GEMM reads
//  wb rows CONTIGUOUSLY (L2/L3-friendly) while each lane's 4 B-fragments are
//  gates f,i,c,o of the SAME j.
// ---------------------------------------------------------------------------
__global__ void convert_all(const float* __restrict__ h_prev, const float* __restrict__ x_t,
                            const float* __restrict__ Wf, const float* __restrict__ Wi,
                            const float* __restrict__ Wc, const float* __restrict__ Wo,
                            u16* __restrict__ comb, u16* __restrict__ wb) {
    const int bid = blockIdx.x;
    const float* src;
    u16* dst;
    if (bid < 8192) {
        int base = (bid * 256 + (int)threadIdx.x) * 8;   // < 2^24
        int row = base >> 12, col = base & 4095;
        src = (col < H_DIM) ? h_prev + (size_t)row * H_DIM + col
                            : x_t    + (size_t)row * I_DIM + (col - H_DIM);
        dst = comb + base;
    } else {
        long long base = ((long long)(bid - 8192) * 256 + threadIdx.x) * 8;
        int n = (int)(base >> 12), col = (int)(base & 4095);
        int row128 = n & 127;
        int g = (row128 >> 4) & 3;
        int j = (n >> 7) * 32 + ((row128 >> 6) << 4) + (row128 & 15);
        const float* W = (g == 0) ? Wf : (g == 1) ? Wi : (g == 2) ? Wc : Wo;
        src = W + (size_t)j * K_DIM + col;
        dst = wb + base;
    }
    float4 v0 = *(const float4*)src;
    float4 v1 = *(const float4*)(src + 4);
    ushort8_t o = { f2bf(v0.x), f2bf(v0.y), f2bf(v0.z), f2bf(v0.w),
                    f2bf(v1.x), f2bf(v1.y), f2bf(v1.z), f2bf(v1.w) };
    *(ushort8_t*)dst = o;
}

// ---------------------------------------------------------------------------
// Kernel 2: fused GEMM + LSTM epilogue.
// m97 structure: 128x128 tile, BK=32, global_load_lds x16, mfma 16x16x32 bf16.
// B rows contiguous from gate-permuted wb; bfr[0..3] = f,i,c,o for one j.
// sched_barrier(0) after the K-loop: keep ALL epilogue-only state (biases,
// addresses, j) out of the loop's live range.  [R3 regression: VGPR 68->88,
// occupancy 23%, MfmaUtil 28 -- hoisted epilogue state cost a resident block]
// ---------------------------------------------------------------------------
__global__ __launch_bounds__(256) void gemm_lstm(const u16* __restrict__ A,
                                                 const u16* __restrict__ Bm,
                                                 const float* __restrict__ c_prev,
                                                 const float* __restrict__ bf_,
                                                 const float* __restrict__ bi_,
                                                 const float* __restrict__ bc_,
                                                 const float* __restrict__ bo_,
                                                 float* __restrict__ out) {
    __shared__ u16 lsA[128 * 32];
    __shared__ u16 lsB[128 * 32];

    const int tid   = threadIdx.x;
    const int lane  = tid & 63;
    const int wave  = tid >> 6;
    const int wm    = (wave & 1) * 64;   // batch-row base within tile
    const int wpart = wave >> 1;         // 0/1: j half
    const int wn    = wpart * 64;        // LDS B row base
    const int quad  = lane >> 4;         // 0..3
    const int r     = lane & 15;         // 0..15
    const int mb    = blockIdx.y * 128;  // batch tile
    const int nbT   = blockIdx.x * 128;  // wb row tile (contiguous)

    floatx4 acc[4][4];
#pragma unroll
    for (int i = 0; i < 4; i++)
#pragma unroll
        for (int g = 0; g < 4; g++)
            acc[i][g] = (floatx4){0.f, 0.f, 0.f, 0.f};

    for (int kt = 0; kt < K_DIM; kt += 32) {
        __syncthreads();
#pragma unroll
        for (int s = 0; s < 2; s++) {
            int c   = tid + s * 256;          // chunk 0..511, 16B each
            int row = c >> 2;                 // 0..127
            int ko  = (c & 3) * 8;            // bf16 elems
            gload16(A  + (size_t)(mb + row) * K_DIM + kt + ko, (char*)lsA + c * 16);
            gload16(Bm + (size_t)(nbT + row) * K_DIM + kt + ko, (char*)lsB + c * 16);
        }
        __syncthreads();

        bf16x8 af[4], bfr[4];
#pragma unroll
        for (int i = 0; i < 4; i++)
            af[i] = *(const bf16x8*)&lsA[(wm + i * 16 + r) * 32 + quad * 8];
#pragma unroll
        for (int g = 0; g < 4; g++)
            bfr[g] = *(const bf16x8*)&lsB[(wn + g * 16 + r) * 32 + quad * 8];
#pragma unroll
        for (int i = 0; i < 4; i++)
#pragma unroll
            for (int g = 0; g < 4; g++)
                acc[i][g] = __builtin_amdgcn_mfma_f32_16x16x32_bf16(
                    af[i], bfr[g], acc[i][g], 0, 0, 0);
    }

    // Fence: nothing below may be scheduled above this point (prevents the
    // epilogue's loads/address math from living across the K-loop).
    __builtin_amdgcn_sched_barrier(0);

    // In-register LSTM epilogue.
    // C/D layout: col = lane&15 (j within fragment), row = quad*4 + reg.
    const int j = blockIdx.x * 32 + wpart * 16 + r;
    const float bfv = bf_[j], biv = bi_[j], bcv = bc_[j], bov = bo_[j];
    const float* cp = c_prev + (size_t)(mb + wm + quad * 4) * H_DIM + j;
    float* oh = out + (size_t)(mb + wm + quad * 4) * H_DIM + j;
    float* oc = oh + (size_t)B_DIM * H_DIM;
#pragma unroll
    for (int i = 0; i < 4; i++) {
#pragma unroll
        for (int rg = 0; rg < 4; rg++) {
            size_t off = (size_t)(i * 16 + rg) * H_DIM;
            float gf = acc[i][0][rg] + bfv;
            float gi = acc[i][1][rg] + biv;
            float gc = acc[i][2][rg] + bcv;
            float go = acc[i][3][rg] + bov;
            float f  = fast_sig(gf);
            float ii = fast_sig(gi);
            float ct = fast_tanh(gc);
            float oo = fast_sig(go);
            float c = f * cp[off] + ii * ct;
            float h = oo * fast_tanh(c);
            oh[off] = h;
            oc[off] = c;
        }
    }
}

// ---------------------------------------------------------------------------
// Fallback (only if ws_size < 96 MiB): naive fp32, correct but slow.
// ---------------------------------------------------------------------------
__global__ void lstm_naive(const float* __restrict__ x_t, const float* __restrict__ h_prev,
                           const float* __restrict__ c_prev,
                           const float* __restrict__ Wf, const float* __restrict__ bf_,
                           const float* __restrict__ Wi, const float* __restrict__ bi_,
                           const float* __restrict__ Wc, const float* __restrict__ bc_,
                           const float* __restrict__ Wo, const float* __restrict__ bo_,
                           float* __restrict__ out) {
    int j = blockIdx.x * blockDim.x + threadIdx.x;  // 0..2047
    int b = blockIdx.y;                             // 0..4095
    const float* hrow = h_prev + (long long)b * H_DIM;
    const float* xrow = x_t   + (long long)b * I_DIM;
    const float* wf = Wf + (long long)j * K_DIM;
    const float* wi = Wi + (long long)j * K_DIM;
    const float* wc = Wc + (long long)j * K_DIM;
    const float* wo = Wo + (long long)j * K_DIM;
    float af = bf_[j], ai = bi_[j], ac = bc_[j], ao = bo_[j];
    for (int k = 0; k < H_DIM; k += 4) {
        float4 v = *(const float4*)(hrow + k);
        float4 a = *(const float4*)(wf + k);
        float4 bqi = *(const float4*)(wi + k);
        float4 cq = *(const float4*)(wc + k);
        float4 dq = *(const float4*)(wo + k);
        af += v.x*a.x + v.y*a.y + v.z*a.z + v.w*a.w;
        ai += v.x*bqi.x + v.y*bqi.y + v.z*bqi.z + v.w*bqi.w;
        ac += v.x*cq.x + v.y*cq.y + v.z*cq.z + v.w*cq.w;
        ao += v.x*dq.x + v.y*dq.y + v.z*dq.z + v.w*dq.w;
    }
    for (int k = 0; k < I_DIM; k += 4) {
        float4 v = *(const float4*)(xrow + k);
        float4 a = *(const float4*)(wf + H_DIM + k);
        float4 bqi = *(const float4*)(wi + H_DIM + k);
        float4 cq = *(const float4*)(wc + H_DIM + k);
        float4 dq = *(const float4*)(wo + H_DIM + k);
        af += v.x*a.x + v.y*a.y + v.z*a.z + v.w*a.w;
        ai += v.x*bqi.x + v.y*bqi.y + v.z*bqi.z + v.w*bqi.w;
        ac += v.x*cq.x + v.y*cq.y + v.z*cq.z + v.w*cq.w;
        ao += v.x*dq.x + v.y*dq.y + v.z*dq.z + v.w*dq.w;
    }
    float f  = 1.f / (1.f + __expf(-af));
    float ii = 1.f / (1.f + __expf(-ai));
    float ct = tanhf(ac);
    float oo = 1.f / (1.f + __expf(-ao));
    int t = b * H_DIM + j;
    float c = f * c_prev[t] + ii * ct;
    out[t] = oo * tanhf(c);
    out[B_DIM * H_DIM + t] = c;
}

extern "C" void kernel_launch(void* const* d_in, const int* in_sizes, int n_in,
                              void* d_out, int out_size, void* d_ws, size_t ws_size,
                              hipStream_t stream) {
    const float* x_t    = (const float*)d_in[0];
    const float* h_prev = (const float*)d_in[1];
    const float* c_prev = (const float*)d_in[2];
    const float* Wf = (const float*)d_in[3];  const float* bf_ = (const float*)d_in[4];
    const float* Wi = (const float*)d_in[5];  const float* bi_ = (const float*)d_in[6];
    const float* Wc = (const float*)d_in[7];  const float* bc_ = (const float*)d_in[8];
    const float* Wo = (const float*)d_in[9];  const float* bo_ = (const float*)d_in[10];
    float* out = (float*)d_out;

    const size_t comb_elems = (size_t)B_DIM * K_DIM;   // 16.7M u16
    const size_t wb_elems   = (size_t)N4 * K_DIM;      // 33.5M u16
    const size_t need = (comb_elems + wb_elems) * sizeof(u16);  // 96 MiB

    if (ws_size >= need) {
        u16* comb = (u16*)d_ws;
        u16* wb   = comb + comb_elems;
        convert_all<<<24576, 256, 0, stream>>>(h_prev, x_t, Wf, Wi, Wc, Wo, comb, wb);
        dim3 grid(N4 / 128, B_DIM / 128);  // (64, 32)
        gemm_lstm<<<grid, 256, 0, stream>>>(comb, wb, c_prev, bf_, bi_, bc_, bo_, out);
    } else {
        dim3 grid(H_DIM / 256, B_DIM);
        lstm_naive<<<grid, 256, 0, stream>>>(x_t, h_prev, c_prev,
                                             Wf, bf_, Wi, bi_, Wc, bc_, Wo, bo_, out);
    }
}